// Round 1
// 124.858 us; speedup vs baseline: 1.1934x; 1.1934x over previous
//
#include <hip/hip_runtime.h>
#include <hip/hip_bf16.h>

// Shapes (fixed by the problem)
#define NMOVES 4096
#define LW     15
#define DIM    1024
#define VOC    32
#define NROW   480   // VOC * LW distinct (token, position) rows
#define MROW   512   // padded row count (rows 480..511 are zeros in Eb)

#define GSPLIT 4            // gram K-split factor
#define KSEG   (DIM/GSPLIT) // 256
#define GN     512          // gram plane leading dimension (guard-free)

typedef __attribute__((ext_vector_type(8))) short  short8;   // 8 bf16 (4 VGPRs)
typedef __attribute__((ext_vector_type(4))) float  floatx4;  // MFMA C/D

__device__ __forceinline__ unsigned short f2b(float f) {
  unsigned int x;
  __builtin_memcpy(&x, &f, 4);
  x = x + 0x7FFFu + ((x >> 16) & 1u);  // round-to-nearest-even
  return (unsigned short)(x >> 16);
}
__device__ __forceinline__ float b2f(unsigned short u) {
  unsigned int x = ((unsigned int)u) << 16;
  float f;
  __builtin_memcpy(&f, &x, 4);
  return f;
}

#define LDK 72   // 64 + 8 bf16 pad: 144 B row stride, 16B-aligned

// ---------------------------------------------------------------------------
// K0: one-shot bf16 pre-conversion.
//   Eb[512,1024] = bf16(letter[t] + pos[l])  (rows >= 480 zeroed)
//   Wb[3][1024,1024] = bf16(Wq / Wk / Wv)
// 8 elems per thread; grid sized exactly (no stride loop).
// ---------------------------------------------------------------------------
__global__ __launch_bounds__(256) void prep(
    const float* __restrict__ letter, const float* __restrict__ pos,
    const float* __restrict__ Wq, const float* __restrict__ Wk,
    const float* __restrict__ Wv,
    unsigned short* __restrict__ Eb, unsigned short* __restrict__ Wb) {
  const int id = blockIdx.x * 256 + threadIdx.x;   // one 8-elem chunk
  const int ECHUNK = MROW * DIM / 8;               // 65536
  const int WCHUNK = DIM * DIM / 8;                // 131072 (2^17)

  if (id < ECHUNK) {
    const int row = id >> 7;            // 128 chunks per row
    const int c   = (id & 127) << 3;
    ushort4 o0 = make_ushort4(0, 0, 0, 0), o1 = o0;
    if (row < NROW) {
      const int t = row / LW;
      const int l = row - t * LW;
      const float* la = letter + (size_t)t * DIM + c;
      const float* lp = pos    + (size_t)l * DIM + c;
      float4 x0 = *reinterpret_cast<const float4*>(la);
      float4 x1 = *reinterpret_cast<const float4*>(la + 4);
      float4 p0 = *reinterpret_cast<const float4*>(lp);
      float4 p1 = *reinterpret_cast<const float4*>(lp + 4);
      o0.x = f2b(x0.x + p0.x); o0.y = f2b(x0.y + p0.y);
      o0.z = f2b(x0.z + p0.z); o0.w = f2b(x0.w + p0.w);
      o1.x = f2b(x1.x + p1.x); o1.y = f2b(x1.y + p1.y);
      o1.z = f2b(x1.z + p1.z); o1.w = f2b(x1.w + p1.w);
    }
    *reinterpret_cast<ushort4*>(Eb + (size_t)row * DIM + c)     = o0;
    *reinterpret_cast<ushort4*>(Eb + (size_t)row * DIM + c + 4) = o1;
  } else {
    const int wi = id - ECHUNK;                    // 0 .. 3*WCHUNK-1
    const int m  = wi >> 17;                       // which matrix
    const int rem = wi & (WCHUNK - 1);
    const float* src = (m == 0) ? Wq : (m == 1) ? Wk : Wv;
    const float* p = src + (size_t)rem * 8;
    float4 x0 = *reinterpret_cast<const float4*>(p);
    float4 x1 = *reinterpret_cast<const float4*>(p + 4);
    ushort4 o0, o1;
    o0.x = f2b(x0.x); o0.y = f2b(x0.y); o0.z = f2b(x0.z); o0.w = f2b(x0.w);
    o1.x = f2b(x1.x); o1.y = f2b(x1.y); o1.z = f2b(x1.z); o1.w = f2b(x1.w);
    unsigned short* dst = Wb + (size_t)m * DIM * DIM + (size_t)rem * 8;
    *reinterpret_cast<ushort4*>(dst)     = o0;
    *reinterpret_cast<ushort4*>(dst + 4) = o1;
  }
}

// ---------------------------------------------------------------------------
// K1: QKV projection, pure bf16 staging with register-prefetch double buffer.
// C[512,1024] = Eb · Wb[z]^T (+bias), output stored bf16 (Qb/Kb/Vb).
// 64x64 tile, 256 thr = 4 waves (2x2), wave does 32x32 via 2x2 fragments of
// mfma_f32_16x16x32_bf16 (fp32 acc). No bounds guards (padded buffers).
// ---------------------------------------------------------------------------
__global__ __launch_bounds__(256) void qkv_fused(
    const unsigned short* __restrict__ Eb, const unsigned short* __restrict__ Wb,
    const float* __restrict__ bq, const float* __restrict__ bk,
    const float* __restrict__ bv,
    unsigned short* __restrict__ Qb, unsigned short* __restrict__ Kb,
    unsigned short* __restrict__ Vb) {
  __shared__ __attribute__((aligned(16))) unsigned short lA[64 * LDK];
  __shared__ __attribute__((aligned(16))) unsigned short lB[64 * LDK];

  const unsigned short* W = Wb + (size_t)blockIdx.z * DIM * DIM;
  const float* bias = (blockIdx.z == 0) ? bq : (blockIdx.z == 1) ? bk : bv;
  unsigned short* O = (blockIdx.z == 0) ? Qb : (blockIdx.z == 1) ? Kb : Vb;

  const int bm0 = blockIdx.x * 64;   // row tile (8 tiles cover 512 rows)
  const int bn0 = blockIdx.y * 64;   // col tile (16 tiles)

  const int tid  = threadIdx.x;
  const int lane = tid & 63;
  const int wave = tid >> 6;
  const int wr   = wave >> 1;
  const int wc   = wave & 1;
  const int quad = lane >> 4;
  const int l16  = lane & 15;

  const int srow = tid >> 3;          // 32 rows per half
  const int scol = (tid & 7) << 3;    // 8 bf16 (16B) per thread

  const unsigned short* As = Eb + (size_t)(bm0 + srow) * DIM + scol;
  const unsigned short* Bs = W  + (size_t)(bn0 + srow) * DIM + scol;

  // prefetch tile 0 into registers
  short8 ra0 = *reinterpret_cast<const short8*>(As);
  short8 ra1 = *reinterpret_cast<const short8*>(As + 32 * DIM);
  short8 rb0 = *reinterpret_cast<const short8*>(Bs);
  short8 rb1 = *reinterpret_cast<const short8*>(Bs + 32 * DIM);

  floatx4 acc[2][2];
#pragma unroll
  for (int i = 0; i < 2; ++i)
#pragma unroll
    for (int j = 0; j < 2; ++j) acc[i][j] = (floatx4){0.f, 0.f, 0.f, 0.f};

  for (int k0 = 0; k0 < DIM; k0 += 64) {
    *reinterpret_cast<short8*>(lA + srow * LDK + scol)        = ra0;
    *reinterpret_cast<short8*>(lA + (srow + 32) * LDK + scol) = ra1;
    *reinterpret_cast<short8*>(lB + srow * LDK + scol)        = rb0;
    *reinterpret_cast<short8*>(lB + (srow + 32) * LDK + scol) = rb1;
    __syncthreads();
    if (k0 + 64 < DIM) {  // issue next-tile loads; MFMA below hides latency
      ra0 = *reinterpret_cast<const short8*>(As + k0 + 64);
      ra1 = *reinterpret_cast<const short8*>(As + 32 * DIM + k0 + 64);
      rb0 = *reinterpret_cast<const short8*>(Bs + k0 + 64);
      rb1 = *reinterpret_cast<const short8*>(Bs + 32 * DIM + k0 + 64);
    }
#pragma unroll
    for (int kk = 0; kk < 64; kk += 32) {
      short8 a0 = *reinterpret_cast<const short8*>(lA + (wr * 32 + l16) * LDK + kk + quad * 8);
      short8 a1 = *reinterpret_cast<const short8*>(lA + (wr * 32 + 16 + l16) * LDK + kk + quad * 8);
      short8 b0 = *reinterpret_cast<const short8*>(lB + (wc * 32 + l16) * LDK + kk + quad * 8);
      short8 b1 = *reinterpret_cast<const short8*>(lB + (wc * 32 + 16 + l16) * LDK + kk + quad * 8);
      acc[0][0] = __builtin_amdgcn_mfma_f32_16x16x32_bf16(a0, b0, acc[0][0], 0, 0, 0);
      acc[0][1] = __builtin_amdgcn_mfma_f32_16x16x32_bf16(a0, b1, acc[0][1], 0, 0, 0);
      acc[1][0] = __builtin_amdgcn_mfma_f32_16x16x32_bf16(a1, b0, acc[1][0], 0, 0, 0);
      acc[1][1] = __builtin_amdgcn_mfma_f32_16x16x32_bf16(a1, b1, acc[1][1], 0, 0, 0);
    }
    __syncthreads();
  }

#pragma unroll
  for (int mi = 0; mi < 2; ++mi) {
#pragma unroll
    for (int ni = 0; ni < 2; ++ni) {
      const int gcol = bn0 + wc * 32 + ni * 16 + l16;
      const float bval = bias[gcol];
#pragma unroll
      for (int i = 0; i < 4; ++i) {
        const int grow = bm0 + wr * 32 + mi * 16 + quad * 4 + i;
        O[(size_t)grow * DIM + gcol] = f2b(acc[mi][ni][i] + bval);
      }
    }
  }
}

// ---------------------------------------------------------------------------
// K2: Gram partials. Gpart[p][512,512] = Qb·Kb^T over K-segment p (256 wide).
// Grid 8x8x4 = 256 blocks, 4 K-iters each, register-prefetch double buffer.
// ---------------------------------------------------------------------------
__global__ __launch_bounds__(256) void gram_split(
    const unsigned short* __restrict__ Qb, const unsigned short* __restrict__ Kb,
    float* __restrict__ Gpart) {
  __shared__ __attribute__((aligned(16))) unsigned short lA[64 * LDK];
  __shared__ __attribute__((aligned(16))) unsigned short lB[64 * LDK];

  const int bm0 = blockIdx.x * 64;
  const int bn0 = blockIdx.y * 64;
  const int kbase = blockIdx.z * KSEG;
  float* Gout = Gpart + (size_t)blockIdx.z * GN * GN;

  const int tid  = threadIdx.x;
  const int lane = tid & 63;
  const int wave = tid >> 6;
  const int wr   = wave >> 1;
  const int wc   = wave & 1;
  const int quad = lane >> 4;
  const int l16  = lane & 15;
  const int srow = tid >> 3;
  const int scol = (tid & 7) << 3;

  const unsigned short* As = Qb + (size_t)(bm0 + srow) * DIM + kbase + scol;
  const unsigned short* Bs = Kb + (size_t)(bn0 + srow) * DIM + kbase + scol;

  short8 ra0 = *reinterpret_cast<const short8*>(As);
  short8 ra1 = *reinterpret_cast<const short8*>(As + 32 * DIM);
  short8 rb0 = *reinterpret_cast<const short8*>(Bs);
  short8 rb1 = *reinterpret_cast<const short8*>(Bs + 32 * DIM);

  floatx4 acc[2][2];
#pragma unroll
  for (int i = 0; i < 2; ++i)
#pragma unroll
    for (int j = 0; j < 2; ++j) acc[i][j] = (floatx4){0.f, 0.f, 0.f, 0.f};

  for (int k0 = 0; k0 < KSEG; k0 += 64) {
    *reinterpret_cast<short8*>(lA + srow * LDK + scol)        = ra0;
    *reinterpret_cast<short8*>(lA + (srow + 32) * LDK + scol) = ra1;
    *reinterpret_cast<short8*>(lB + srow * LDK + scol)        = rb0;
    *reinterpret_cast<short8*>(lB + (srow + 32) * LDK + scol) = rb1;
    __syncthreads();
    if (k0 + 64 < KSEG) {
      ra0 = *reinterpret_cast<const short8*>(As + k0 + 64);
      ra1 = *reinterpret_cast<const short8*>(As + 32 * DIM + k0 + 64);
      rb0 = *reinterpret_cast<const short8*>(Bs + k0 + 64);
      rb1 = *reinterpret_cast<const short8*>(Bs + 32 * DIM + k0 + 64);
    }
#pragma unroll
    for (int kk = 0; kk < 64; kk += 32) {
      short8 a0 = *reinterpret_cast<const short8*>(lA + (wr * 32 + l16) * LDK + kk + quad * 8);
      short8 a1 = *reinterpret_cast<const short8*>(lA + (wr * 32 + 16 + l16) * LDK + kk + quad * 8);
      short8 b0 = *reinterpret_cast<const short8*>(lB + (wc * 32 + l16) * LDK + kk + quad * 8);
      short8 b1 = *reinterpret_cast<const short8*>(lB + (wc * 32 + 16 + l16) * LDK + kk + quad * 8);
      acc[0][0] = __builtin_amdgcn_mfma_f32_16x16x32_bf16(a0, b0, acc[0][0], 0, 0, 0);
      acc[0][1] = __builtin_amdgcn_mfma_f32_16x16x32_bf16(a0, b1, acc[0][1], 0, 0, 0);
      acc[1][0] = __builtin_amdgcn_mfma_f32_16x16x32_bf16(a1, b0, acc[1][0], 0, 0, 0);
      acc[1][1] = __builtin_amdgcn_mfma_f32_16x16x32_bf16(a1, b1, acc[1][1], 0, 0, 0);
    }
    __syncthreads();
  }

#pragma unroll
  for (int mi = 0; mi < 2; ++mi) {
#pragma unroll
    for (int ni = 0; ni < 2; ++ni) {
      const int gcol = bn0 + wc * 32 + ni * 16 + l16;
#pragma unroll
      for (int i = 0; i < 4; ++i) {
        const int grow = bm0 + wr * 32 + mi * 16 + quad * 4 + i;
        Gout[(size_t)grow * GN + gcol] = acc[mi][ni][i];
      }
    }
  }
}

// ---------------------------------------------------------------------------
// K3: per-move attention. One block per move. Tokens dtype auto-detected.
// S[l][j] = sum_p Gpart[p][r_l,r_j]; P = softmax_j(S); w_j = 2*sum_l P[l][j];
// out[m] = sum_j w_j * Vb[r_j]   (bf16 V, fp32 out)
// ---------------------------------------------------------------------------
__global__ __launch_bounds__(256) void attn_out_k(
    const void* __restrict__ tokens_raw, const float* __restrict__ Gpart,
    const unsigned short* __restrict__ Vb, float* __restrict__ out) {
  __shared__ int   ridx[LW];
  __shared__ float S[LW][16];
  __shared__ float w[16];
  __shared__ int   is64_s;
  const int m = blockIdx.x;
  const int tid = threadIdx.x;

  const unsigned int* u32 = (const unsigned int*)tokens_raw;
  if (tid < 64) {  // int64 tokens (<32) have all odd 32-bit words zero
    unsigned int v = u32[2 * tid + 1];
    unsigned long long nz = __ballot(v != 0);
    if (tid == 0) is64_s = (nz == 0ULL) ? 1 : 0;
  }
  __syncthreads();

  if (tid < LW) {
    int t;
    if (is64_s) t = (int)((const long long*)tokens_raw)[m * LW + tid];
    else        t = ((const int*)tokens_raw)[m * LW + tid];
    ridx[tid] = t * LW + tid;
  }
  __syncthreads();

  if (tid < LW * LW) {
    const int l = tid / LW;
    const int j = tid - l * LW;
    const size_t off = (size_t)ridx[l] * GN + ridx[j];
    float s = 0.f;
#pragma unroll
    for (int p = 0; p < GSPLIT; ++p) s += Gpart[(size_t)p * GN * GN + off];
    S[l][j] = s;
  }
  __syncthreads();

  if (tid < LW) {  // row softmax (over j)
    float mx = -1e30f;
#pragma unroll
    for (int j = 0; j < LW; ++j) mx = fmaxf(mx, S[tid][j]);
    float s = 0.f;
#pragma unroll
    for (int j = 0; j < LW; ++j) { float e = __expf(S[tid][j] - mx); S[tid][j] = e; s += e; }
    const float inv = 1.0f / s;
#pragma unroll
    for (int j = 0; j < LW; ++j) S[tid][j] *= inv;
  }
  __syncthreads();

  if (tid < LW) {  // column weights, with the 2x folded in
    float s = 0.f;
#pragma unroll
    for (int l = 0; l < LW; ++l) s += S[l][tid];
    w[tid] = 2.0f * s;
  }
  __syncthreads();

  const int e0 = tid * 4;  // 256 threads x 4 = 1024 outputs
  float a0 = 0.f, a1 = 0.f, a2 = 0.f, a3 = 0.f;
#pragma unroll
  for (int j = 0; j < LW; ++j) {
    const float wj = w[j];
    ushort4 vv = *reinterpret_cast<const ushort4*>(Vb + (size_t)ridx[j] * DIM + e0);
    a0 += wj * b2f(vv.x);
    a1 += wj * b2f(vv.y);
    a2 += wj * b2f(vv.z);
    a3 += wj * b2f(vv.w);
  }
  *reinterpret_cast<float4*>(out + (size_t)m * DIM + e0) =
      make_float4(a0, a1, a2, a3);
}

// ---------------------------------------------------------------------------
extern "C" void kernel_launch(void* const* d_in, const int* in_sizes, int n_in,
                              void* d_out, int out_size, void* d_ws, size_t ws_size,
                              hipStream_t stream) {
  const void*  tokens = d_in[0];
  const float* letter = (const float*)d_in[1];
  const float* pos    = (const float*)d_in[2];
  const float* Wq     = (const float*)d_in[3];
  const float* bq     = (const float*)d_in[4];
  const float* Wk     = (const float*)d_in[5];
  const float* bk     = (const float*)d_in[6];
  const float* Wv     = (const float*)d_in[7];
  const float* bv     = (const float*)d_in[8];
  float*       outp   = (float*)d_out;   // reference output dtype = float32

  char* ws = (char*)d_ws;
  const size_t EB_SZ = (size_t)MROW * DIM * 2;          // 1 MB
  const size_t WB_SZ = (size_t)3 * DIM * DIM * 2;       // 6 MB
  const size_t OB_SZ = (size_t)MROW * DIM * 2;          // 1 MB each
  unsigned short* Eb = (unsigned short*)(ws);
  unsigned short* Wb = (unsigned short*)(ws + EB_SZ);
  unsigned short* Qb = (unsigned short*)(ws + EB_SZ + WB_SZ);
  unsigned short* Kb = (unsigned short*)(ws + EB_SZ + WB_SZ + OB_SZ);
  unsigned short* Vb = (unsigned short*)(ws + EB_SZ + WB_SZ + 2 * OB_SZ);
  float*          Gp = (float*)(ws + EB_SZ + WB_SZ + 3 * OB_SZ);  // 4x512x512x4 = 4 MB

  const int ECHUNK = MROW * DIM / 8;
  const int WCHUNK = DIM * DIM / 8;
  const int PREP_BLOCKS = (ECHUNK + 3 * WCHUNK) / 256;  // 1792, exact

  prep<<<PREP_BLOCKS, 256, 0, stream>>>(letter, pos, Wq, Wk, Wv, Eb, Wb);
  qkv_fused<<<dim3(8, 16, 3), 256, 0, stream>>>(Eb, Wb, bq, bk, bv, Qb, Kb, Vb);
  gram_split<<<dim3(8, 8, GSPLIT), 256, 0, stream>>>(Qb, Kb, Gp);
  attn_out_k<<<NMOVES, 256, 0, stream>>>(tokens, Gp, Vb, outp);
}